// Round 1
// baseline (2353.466 us; speedup 1.0000x reference)
//
#include <hip/hip_runtime.h>
#include <hip/hip_bf16.h>

// MHA forward, fp32 baseline (round 0, correctness-first).
// S=2048 B=2 E=1024 H=16 D=64. scale = 1/8.
// ws layout (floats): Qp[BHS*64] | Kp | Vp | wa[B*S*E]  = 64 MB total.
// d_out: out[S,B,E] (4194304 floats) then attn_mean[B,S,S] (8388608 floats).

#define Sq 2048
#define Bb 2
#define Ee 1024
#define Hh 16
#define Dd 64

// ---------------- GEMM 1: QKV projection, scatter to [B,H,S,64] ----------------
// C[M=4096][N=3072] = xb[M][1024] @ qkv_w^T + qkv_b
__global__ __launch_bounds__(256) void qkv_gemm(
    const float* __restrict__ x, const float* __restrict__ w,
    const float* __restrict__ bias,
    float* __restrict__ Qp, float* __restrict__ Kp, float* __restrict__ Vp)
{
    __shared__ __align__(16) float As[8][132];
    __shared__ __align__(16) float Bs[8][132];
    const int t  = threadIdx.x;
    const int m0 = blockIdx.y * 128;
    const int n0 = blockIdx.x * 128;
    const int tx = t & 15, ty = t >> 4;
    const int lr = t >> 1;          // 0..127
    const int lc = (t & 1) * 4;     // 0 or 4
    const int ma = m0 + lr;
    const int bb = ma >> 11, ss = ma & 2047;
    const float* arow = x + (ss * Bb + bb) * Ee;   // xb[m][k] = x[s][b][k]
    const float* brow = w + (n0 + lr) * Ee;
    float acc[8][8];
#pragma unroll
    for (int i = 0; i < 8; i++)
#pragma unroll
        for (int j = 0; j < 8; j++) acc[i][j] = 0.f;

    for (int k0 = 0; k0 < Ee; k0 += 8) {
        float4 a4 = *(const float4*)(arow + k0 + lc);
        float4 b4 = *(const float4*)(brow + k0 + lc);
        __syncthreads();
        As[lc+0][lr] = a4.x; As[lc+1][lr] = a4.y; As[lc+2][lr] = a4.z; As[lc+3][lr] = a4.w;
        Bs[lc+0][lr] = b4.x; Bs[lc+1][lr] = b4.y; Bs[lc+2][lr] = b4.z; Bs[lc+3][lr] = b4.w;
        __syncthreads();
#pragma unroll
        for (int kk = 0; kk < 8; kk++) {
            float a[8], bv[8];
            *(float4*)&a[0]  = *(const float4*)&As[kk][ty*8];
            *(float4*)&a[4]  = *(const float4*)&As[kk][ty*8+4];
            *(float4*)&bv[0] = *(const float4*)&Bs[kk][tx*8];
            *(float4*)&bv[4] = *(const float4*)&Bs[kk][tx*8+4];
#pragma unroll
            for (int i = 0; i < 8; i++)
#pragma unroll
                for (int j = 0; j < 8; j++) acc[i][j] += a[i] * bv[j];
        }
    }
    // epilogue: n tile of 8 cols lies in a single (which, head, dd) 64-group
    const int n_base = n0 + tx*8;
    const int which  = n_base >> 10;
    const int hh     = (n_base & 1023) >> 6;
    const int dd     = n_base & 63;
    float* dst = (which == 0) ? Qp : (which == 1 ? Kp : Vp);
    float bz[8];
#pragma unroll
    for (int j = 0; j < 8; j++) bz[j] = bias[n_base + j];
#pragma unroll
    for (int i = 0; i < 8; i++) {
        int m  = m0 + ty*8 + i;
        int b2 = m >> 11, s2 = m & 2047;
        float* drow = dst + (((b2*Hh) + hh)*Sq + s2)*Dd + dd;
        float4 o1 = {acc[i][0]+bz[0], acc[i][1]+bz[1], acc[i][2]+bz[2], acc[i][3]+bz[3]};
        float4 o2 = {acc[i][4]+bz[4], acc[i][5]+bz[5], acc[i][6]+bz[6], acc[i][7]+bz[7]};
        *(float4*)(drow)     = o1;
        *(float4*)(drow + 4) = o2;
    }
}

// ---------------- Attention: one block per (b, 16 query rows), all 16 heads ----------------
// 512 threads: row r = t>>5 (16 rows), sub-lane u = t&31 owns cols c == u (mod 32).
__global__ __launch_bounds__(512) void attn_kernel(
    const float* __restrict__ Qp, const float* __restrict__ Kp, const float* __restrict__ Vp,
    const float* __restrict__ attn_mask, const unsigned char* __restrict__ kpm,
    float* __restrict__ wa, float* __restrict__ attn_mean)
{
    const int t  = threadIdx.x;
    const int bq = blockIdx.x;          // 0..255
    const int b  = bq >> 7;
    const int q0 = (bq & 127) << 4;     // 16 rows per block
    const int r  = t >> 5;              // 0..15
    const int u  = t & 31;              // 0..31

    __shared__ __align__(16) float Qs[16][68];
    __shared__ __align__(16) float KVs[64][68];
    __shared__ float kpmf[Sq];
    __shared__ __hip_bfloat16 Ss[16][2064];   // thread-private score/prob storage

    for (int i = t; i < Sq; i += 512)
        kpmf[i] = kpm[b*Sq + i] ? -1e30f : 0.0f;

    const float* am_row = attn_mask + (size_t)(q0 + r) * Sq;
    float* aout = attn_mean + (size_t)(b*Sq + q0 + r) * Sq;

    for (int h = 0; h < Hh; h++) {
        const float* qbase = Qp + (size_t)((b*Hh + h)*Sq + q0) * Dd;
        const float* kbase = Kp + (size_t)(b*Hh + h) * Sq * Dd;
        const float* vbase = Vp + (size_t)(b*Hh + h) * Sq * Dd;

        __syncthreads();                 // protect Qs readers from previous head
        for (int i = t; i < 256; i += 512) {     // 16 rows x 16 float4
            int row = i >> 4, c4 = (i & 15) * 4;
            *(float4*)&Qs[row][c4] = *(const float4*)(qbase + row*Dd + c4);
        }
        __syncthreads();

        float qreg[64];
#pragma unroll
        for (int i = 0; i < 16; i++) {
            float4 tmp = *(const float4*)&Qs[r][i*4];
            qreg[i*4+0] = tmp.x; qreg[i*4+1] = tmp.y; qreg[i*4+2] = tmp.z; qreg[i*4+3] = tmp.w;
        }

        // ---- scores ----
        float mx = -3e38f;
        for (int ct = 0; ct < 32; ct++) {
            __syncthreads();
            for (int i = t; i < 1024; i += 512) {   // 64 rows x 16 float4
                int row = i >> 4, c4 = (i & 15) * 4;
                *(float4*)&KVs[row][c4] = *(const float4*)(kbase + (ct*64 + row)*Dd + c4);
            }
            __syncthreads();
#pragma unroll
            for (int jj = 0; jj < 2; jj++) {
                const int cl = jj*32 + u;
                float a = 0.f;
#pragma unroll
                for (int dk = 0; dk < 16; dk++) {
                    float4 k4 = *(const float4*)&KVs[cl][dk*4];
                    a += qreg[dk*4+0]*k4.x + qreg[dk*4+1]*k4.y
                       + qreg[dk*4+2]*k4.z + qreg[dk*4+3]*k4.w;
                }
                const int c = ct*64 + cl;
                float sval = a*0.125f + am_row[c] + kpmf[c];
                Ss[r][c] = __float2bfloat16(sval);
                mx = fmaxf(mx, sval);
            }
        }
#pragma unroll
        for (int off = 1; off <= 16; off <<= 1)
            mx = fmaxf(mx, __shfl_xor(mx, off, 64));

        // ---- exp + sum ----
        float sm = 0.f;
        for (int j = 0; j < 64; j++) {
            int c = j*32 + u;
            float p = __expf(__bfloat162float(Ss[r][c]) - mx);
            sm += p;
            Ss[r][c] = __float2bfloat16(p);
        }
#pragma unroll
        for (int off = 1; off <= 16; off <<= 1)
            sm += __shfl_xor(sm, off, 64);
        const float rl = 1.0f / sm;

        // ---- P@V + attn_mean accumulate ----
        float wap[64];
#pragma unroll
        for (int i = 0; i < 64; i++) wap[i] = 0.f;

        for (int ct = 0; ct < 32; ct++) {
            __syncthreads();
            for (int i = t; i < 1024; i += 512) {
                int row = i >> 4, c4 = (i & 15) * 4;
                *(float4*)&KVs[row][c4] = *(const float4*)(vbase + (ct*64 + row)*Dd + c4);
            }
            __syncthreads();
#pragma unroll
            for (int jj = 0; jj < 2; jj++) {
                const int cl = jj*32 + u;
                const int c  = ct*64 + cl;
                float p  = __bfloat162float(Ss[r][c]) * rl;
                float pm = p * 0.0625f;                 // /16 heads
                aout[c] = (h == 0) ? pm : (aout[c] + pm);   // block-exclusive RMW, L2-hot
#pragma unroll
                for (int dk = 0; dk < 16; dk++) {
                    float4 v4 = *(const float4*)&KVs[cl][dk*4];
                    wap[dk*4+0] += p*v4.x; wap[dk*4+1] += p*v4.y;
                    wap[dk*4+2] += p*v4.z; wap[dk*4+3] += p*v4.w;
                }
            }
        }
        // reduce wap across the 32 lanes of this row
#pragma unroll
        for (int i = 0; i < 64; i++) {
#pragma unroll
            for (int off = 1; off <= 16; off <<= 1)
                wap[i] += __shfl_xor(wap[i], off, 64);
        }
        if (u == 0) {
#pragma unroll
            for (int i = 0; i < 64; i++) Qs[r][i] = wap[i];
        }
        __syncthreads();
        for (int i = t; i < 256; i += 512) {     // 16 rows x 16 float4 -> wa[b,s,h*64+dd]
            int row = i >> 4, c4 = (i & 15) * 4;
            *(float4*)(wa + (size_t)(b*Sq + q0 + row)*Ee + h*Dd + c4) =
                *(const float4*)&Qs[row][c4];
        }
    }
}

// ---------------- GEMM 2: output projection ----------------
// out[s,b,:] = wa[b,s,:] @ out_w^T + out_b
__global__ __launch_bounds__(256) void out_gemm(
    const float* __restrict__ wa, const float* __restrict__ w,
    const float* __restrict__ bias, float* __restrict__ outp)
{
    __shared__ __align__(16) float As[8][132];
    __shared__ __align__(16) float Bs[8][132];
    const int t  = threadIdx.x;
    const int m0 = blockIdx.y * 128;
    const int n0 = blockIdx.x * 128;
    const int tx = t & 15, ty = t >> 4;
    const int lr = t >> 1;
    const int lc = (t & 1) * 4;
    const float* arow = wa + (size_t)(m0 + lr) * Ee;
    const float* brow = w + (size_t)(n0 + lr) * Ee;
    float acc[8][8];
#pragma unroll
    for (int i = 0; i < 8; i++)
#pragma unroll
        for (int j = 0; j < 8; j++) acc[i][j] = 0.f;

    for (int k0 = 0; k0 < Ee; k0 += 8) {
        float4 a4 = *(const float4*)(arow + k0 + lc);
        float4 b4 = *(const float4*)(brow + k0 + lc);
        __syncthreads();
        As[lc+0][lr] = a4.x; As[lc+1][lr] = a4.y; As[lc+2][lr] = a4.z; As[lc+3][lr] = a4.w;
        Bs[lc+0][lr] = b4.x; Bs[lc+1][lr] = b4.y; Bs[lc+2][lr] = b4.z; Bs[lc+3][lr] = b4.w;
        __syncthreads();
#pragma unroll
        for (int kk = 0; kk < 8; kk++) {
            float a[8], bv[8];
            *(float4*)&a[0]  = *(const float4*)&As[kk][ty*8];
            *(float4*)&a[4]  = *(const float4*)&As[kk][ty*8+4];
            *(float4*)&bv[0] = *(const float4*)&Bs[kk][tx*8];
            *(float4*)&bv[4] = *(const float4*)&Bs[kk][tx*8+4];
#pragma unroll
            for (int i = 0; i < 8; i++)
#pragma unroll
                for (int j = 0; j < 8; j++) acc[i][j] += a[i] * bv[j];
        }
    }
    const int n_base = n0 + tx*8;
    float bz[8];
#pragma unroll
    for (int j = 0; j < 8; j++) bz[j] = bias[n_base + j];
#pragma unroll
    for (int i = 0; i < 8; i++) {
        int m  = m0 + ty*8 + i;
        int b2 = m >> 11, s2 = m & 2047;
        float* drow = outp + (size_t)(s2*Bb + b2)*Ee + n_base;
        float4 o1 = {acc[i][0]+bz[0], acc[i][1]+bz[1], acc[i][2]+bz[2], acc[i][3]+bz[3]};
        float4 o2 = {acc[i][4]+bz[4], acc[i][5]+bz[5], acc[i][6]+bz[6], acc[i][7]+bz[7]};
        *(float4*)(drow)     = o1;
        *(float4*)(drow + 4) = o2;
    }
}

extern "C" void kernel_launch(void* const* d_in, const int* in_sizes, int n_in,
                              void* d_out, int out_size, void* d_ws, size_t ws_size,
                              hipStream_t stream) {
    const float*         x         = (const float*)d_in[0];
    const float*         attn_mask = (const float*)d_in[1];
    const unsigned char* kpm       = (const unsigned char*)d_in[2];
    const float*         qkv_w     = (const float*)d_in[3];
    const float*         qkv_b     = (const float*)d_in[4];
    const float*         out_w     = (const float*)d_in[5];
    const float*         out_b     = (const float*)d_in[6];

    float* outp      = (float*)d_out;
    float* attn_mean = outp + 4194304;          // S*B*E

    float* ws = (float*)d_ws;                   // needs 64 MB
    float* Qp = ws;
    float* Kp = ws + 4194304;
    float* Vp = ws + 2*4194304;
    float* wa = ws + 3*4194304;

    qkv_gemm<<<dim3(24, 32), 256, 0, stream>>>(x, qkv_w, qkv_b, Qp, Kp, Vp);
    attn_kernel<<<dim3(256), 512, 0, stream>>>(Qp, Kp, Vp, attn_mask, kpm, wa, attn_mean);
    out_gemm<<<dim3(8, 32), 256, 0, stream>>>(wa, out_w, out_b, outp);
}

// Round 2
// 1013.204 us; speedup vs baseline: 2.3228x; 2.3228x over previous
//
#include <hip/hip_runtime.h>
#include <hip/hip_bf16.h>

// MHA forward, round 2: MFMA bf16 attention + recompute-based attn_mean.
// S=2048 B=2 E=1024 H=16 D=64. scale = 1/8.
// ws (40.25 MB): Qp bf16[B,H,S,64] | Kp bf16[B,H,S,64] | Vt bf16[B,H,64,S]
//              | wa fp32[B,S,E] | rl fp32[B,H,S]
// d_out: out[S,B,E] fp32 (4194304) then attn_mean[B,S,S] fp32 (8388608).

#define Sq 2048
#define Bb 2
#define Ee 1024
#define Hh 16
#define Dd 64

typedef __attribute__((ext_vector_type(8))) short bhalf8;   // 8 bf16 (4 VGPRs)
typedef __attribute__((ext_vector_type(4))) float f32x4;

// ---------------- GEMM 1: QKV projection (fp32 compute), bf16 scatter ----------------
// C[M=4096][N=3072] = xb[M][1024] @ qkv_w^T + qkv_b
__global__ __launch_bounds__(256) void qkv_gemm(
    const float* __restrict__ x, const float* __restrict__ w,
    const float* __restrict__ bias,
    __hip_bfloat16* __restrict__ Qp, __hip_bfloat16* __restrict__ Kp,
    __hip_bfloat16* __restrict__ Vt)
{
    __shared__ __align__(16) float As[8][132];
    __shared__ __align__(16) float Bs[8][132];
    const int t  = threadIdx.x;
    const int m0 = blockIdx.y * 128;
    const int n0 = blockIdx.x * 128;
    const int tx = t & 15, ty = t >> 4;
    const int lr = t >> 1;          // 0..127
    const int lc = (t & 1) * 4;     // 0 or 4
    const int ma = m0 + lr;
    const int bb = ma >> 11, ss = ma & 2047;
    const float* arow = x + (ss * Bb + bb) * Ee;   // xb[m][k] = x[s][b][k]
    const float* brow = w + (n0 + lr) * Ee;
    float acc[8][8];
#pragma unroll
    for (int i = 0; i < 8; i++)
#pragma unroll
        for (int j = 0; j < 8; j++) acc[i][j] = 0.f;

    for (int k0 = 0; k0 < Ee; k0 += 8) {
        float4 a4 = *(const float4*)(arow + k0 + lc);
        float4 b4 = *(const float4*)(brow + k0 + lc);
        __syncthreads();
        As[lc+0][lr] = a4.x; As[lc+1][lr] = a4.y; As[lc+2][lr] = a4.z; As[lc+3][lr] = a4.w;
        Bs[lc+0][lr] = b4.x; Bs[lc+1][lr] = b4.y; Bs[lc+2][lr] = b4.z; Bs[lc+3][lr] = b4.w;
        __syncthreads();
#pragma unroll
        for (int kk = 0; kk < 8; kk++) {
            float a[8], bv[8];
            *(float4*)&a[0]  = *(const float4*)&As[kk][ty*8];
            *(float4*)&a[4]  = *(const float4*)&As[kk][ty*8+4];
            *(float4*)&bv[0] = *(const float4*)&Bs[kk][tx*8];
            *(float4*)&bv[4] = *(const float4*)&Bs[kk][tx*8+4];
#pragma unroll
            for (int i = 0; i < 8; i++)
#pragma unroll
                for (int j = 0; j < 8; j++) acc[i][j] += a[i] * bv[j];
        }
    }
    // epilogue: 8 cols lie in one (which, head, dd) group; dd multiple of 8
    const int n_base = n0 + tx*8;
    const int which  = n_base >> 10;
    const int hh     = (n_base & 1023) >> 6;
    const int dd     = n_base & 63;
    float bz[8];
#pragma unroll
    for (int j = 0; j < 8; j++) bz[j] = bias[n_base + j];
    if (which < 2) {
        __hip_bfloat16* dst = (which == 0) ? Qp : Kp;
#pragma unroll
        for (int i = 0; i < 8; i++) {
            int m  = m0 + ty*8 + i;
            int b2 = m >> 11, s2 = m & 2047;
            alignas(16) __hip_bfloat16 tmp[8];
#pragma unroll
            for (int j = 0; j < 8; j++) tmp[j] = __float2bfloat16(acc[i][j] + bz[j]);
            *(uint4*)(dst + ((size_t)(b2*Hh + hh)*Sq + s2)*Dd + dd) = *(const uint4*)tmp;
        }
    } else {
        // V stored transposed: Vt[b][h][d][s]
#pragma unroll
        for (int i = 0; i < 8; i++) {
            int m  = m0 + ty*8 + i;
            int b2 = m >> 11, s2 = m & 2047;
#pragma unroll
            for (int j = 0; j < 8; j++)
                Vt[((size_t)(b2*Hh + hh)*Dd + dd + j)*Sq + s2] =
                    __float2bfloat16(acc[i][j] + bz[j]);
        }
    }
}

// ---------------- Attention core: one block per (b,h,64 q rows), 4 waves ----------------
// Wave w owns q rows [q0+w*16, +16). No __syncthreads (per-wave LDS regions).
__global__ __launch_bounds__(256) void attn_mfma(
    const __hip_bfloat16* __restrict__ Qp, const __hip_bfloat16* __restrict__ Kp,
    const __hip_bfloat16* __restrict__ Vt,
    const float* __restrict__ am, const unsigned char* __restrict__ kpm,
    float* __restrict__ wa, float* __restrict__ rlbuf)
{
    __shared__ __align__(16) __hip_bfloat16 P_lds[4][16][72];  // per-wave P tile, 2-way-free stride
    const int t    = threadIdx.x;
    const int w    = t >> 6;
    const int l    = t & 63;
    const int lm   = l & 15, quad = l >> 4;
    const int blk  = blockIdx.x;       // (bh)*32 + qt
    const int bh   = blk >> 5;
    const int b    = bh >> 4;
    const int h    = bh & 15;
    const int q0   = (blk & 31) * 64 + w * 16;
    const int qrow = q0 + quad * 4;    // C-frag rows are qrow+reg

    const __hip_bfloat16* qbase = Qp + ((size_t)bh*Sq + q0)*Dd;
    const __hip_bfloat16* kbase = Kp + (size_t)bh*Sq*Dd;
    const __hip_bfloat16* vbase = Vt + (size_t)bh*Dd*Sq;

    bhalf8 aq[2];
    aq[0] = *(const bhalf8*)(qbase + lm*Dd + quad*8);
    aq[1] = *(const bhalf8*)(qbase + lm*Dd + quad*8 + 32);

    f32x4 o[4] = {};               // O: 16q x 64d, frag nd covers d = nd*16+lm
    float lsum[4] = {0.f, 0.f, 0.f, 0.f};

    for (int kt = 0; kt < 32; kt++) {
        const int k0 = kt * 64;
        f32x4 s[4] = {};
#pragma unroll
        for (int f = 0; f < 2; f++) {
#pragma unroll
            for (int j = 0; j < 4; j++) {
                bhalf8 bk = *(const bhalf8*)(kbase + (size_t)(k0 + j*16 + lm)*Dd + quad*8 + f*32);
                s[j] = __builtin_amdgcn_mfma_f32_16x16x32_bf16(aq[f], bk, s[j], 0, 0, 0);
            }
        }
        // scale + mask + exp; accumulate row sums; stage P into per-wave LDS (C->A transpose)
#pragma unroll
        for (int j = 0; j < 4; j++) {
            const int key = k0 + j*16 + lm;
            const float km = kpm[b*Sq + key] ? -1e30f : 0.0f;
#pragma unroll
            for (int r = 0; r < 4; r++) {
                float sv = s[j][r]*0.125f + am[(size_t)(qrow + r)*Sq + key] + km;
                float p  = __expf(sv);
                lsum[r] += p;
                P_lds[w][quad*4 + r][j*16 + lm] = __float2bfloat16(p);
            }
        }
        // PV: O += P @ V  (A from LDS, B from transposed V in global)
#pragma unroll
        for (int ks = 0; ks < 2; ks++) {
            bhalf8 ap = *(const bhalf8*)&P_lds[w][lm][ks*32 + quad*8];
#pragma unroll
            for (int nd = 0; nd < 4; nd++) {
                bhalf8 bv = *(const bhalf8*)(vbase + (size_t)(nd*16 + lm)*Sq + k0 + ks*32 + quad*8);
                o[nd] = __builtin_amdgcn_mfma_f32_16x16x32_bf16(ap, bv, o[nd], 0, 0, 0);
            }
        }
    }
    // reduce lsum across the 16 lanes of the quad-group (cols of the row)
    float rl[4];
#pragma unroll
    for (int r = 0; r < 4; r++) {
        float v = lsum[r];
        v += __shfl_xor(v, 1, 64);
        v += __shfl_xor(v, 2, 64);
        v += __shfl_xor(v, 4, 64);
        v += __shfl_xor(v, 8, 64);
        rl[r] = 1.0f / v;
    }
    if (lm == 0) {
#pragma unroll
        for (int r = 0; r < 4; r++) rlbuf[(size_t)bh*Sq + qrow + r] = rl[r];
    }
    // normalize + write wa[b][q][h*64+d]
#pragma unroll
    for (int nd = 0; nd < 4; nd++)
#pragma unroll
        for (int r = 0; r < 4; r++)
            wa[((size_t)b*Sq + qrow + r)*Ee + h*Dd + nd*16 + lm] = o[nd][r] * rl[r];
}

// ---------------- attn_mean by recomputation: block = (b, 16 q rows, 512 keys) ----------------
// Wave w owns keys [kc0 + w*128, +128). Loops all 16 heads, accumulates mean in VGPRs.
__global__ __launch_bounds__(256) void attn_mean_k(
    const __hip_bfloat16* __restrict__ Qp, const __hip_bfloat16* __restrict__ Kp,
    const float* __restrict__ am, const unsigned char* __restrict__ kpm,
    const float* __restrict__ rlbuf, float* __restrict__ attn_mean)
{
    const int t    = threadIdx.x;
    const int w    = t >> 6;
    const int l    = t & 63;
    const int lm   = l & 15, quad = l >> 4;
    const int b    = blockIdx.z;
    const int q0   = blockIdx.y * 16;
    const int kc   = blockIdx.x * 512 + w * 128;
    const int qrow = q0 + quad * 4;

    // hoist mask (reused by all 16 heads)
    float mval[2][4][4];
#pragma unroll
    for (int kt = 0; kt < 2; kt++)
#pragma unroll
        for (int j = 0; j < 4; j++) {
            const int key = kc + kt*64 + j*16 + lm;
            const float km = kpm[b*Sq + key] ? -1e30f : 0.0f;
#pragma unroll
            for (int r = 0; r < 4; r++)
                mval[kt][j][r] = am[(size_t)(qrow + r)*Sq + key] + km;
        }

    float macc[2][4][4];
#pragma unroll
    for (int kt = 0; kt < 2; kt++)
#pragma unroll
        for (int j = 0; j < 4; j++)
#pragma unroll
            for (int r = 0; r < 4; r++) macc[kt][j][r] = 0.f;

    for (int h = 0; h < Hh; h++) {
        const int bh = b*Hh + h;
        const __hip_bfloat16* qbase = Qp + ((size_t)bh*Sq + q0)*Dd;
        const __hip_bfloat16* kbase = Kp + (size_t)bh*Sq*Dd;
        bhalf8 aq0 = *(const bhalf8*)(qbase + lm*Dd + quad*8);
        bhalf8 aq1 = *(const bhalf8*)(qbase + lm*Dd + quad*8 + 32);
        float rl4[4];
#pragma unroll
        for (int r = 0; r < 4; r++)
            rl4[r] = rlbuf[(size_t)bh*Sq + qrow + r] * 0.0625f;   // /H
#pragma unroll
        for (int kt = 0; kt < 2; kt++) {
            const int k0 = kc + kt*64;
            f32x4 s[4] = {};
#pragma unroll
            for (int j = 0; j < 4; j++) {
                bhalf8 bk0 = *(const bhalf8*)(kbase + (size_t)(k0 + j*16 + lm)*Dd + quad*8);
                s[j] = __builtin_amdgcn_mfma_f32_16x16x32_bf16(aq0, bk0, s[j], 0, 0, 0);
                bhalf8 bk1 = *(const bhalf8*)(kbase + (size_t)(k0 + j*16 + lm)*Dd + quad*8 + 32);
                s[j] = __builtin_amdgcn_mfma_f32_16x16x32_bf16(aq1, bk1, s[j], 0, 0, 0);
            }
#pragma unroll
            for (int j = 0; j < 4; j++)
#pragma unroll
                for (int r = 0; r < 4; r++)
                    macc[kt][j][r] += __expf(s[j][r]*0.125f + mval[kt][j][r]) * rl4[r];
        }
    }
#pragma unroll
    for (int kt = 0; kt < 2; kt++)
#pragma unroll
        for (int j = 0; j < 4; j++)
#pragma unroll
            for (int r = 0; r < 4; r++)
                attn_mean[((size_t)b*Sq + qrow + r)*Sq + kc + kt*64 + j*16 + lm] =
                    macc[kt][j][r];
}

// ---------------- GEMM 2: output projection (fp32, unchanged) ----------------
__global__ __launch_bounds__(256) void out_gemm(
    const float* __restrict__ wa, const float* __restrict__ w,
    const float* __restrict__ bias, float* __restrict__ outp)
{
    __shared__ __align__(16) float As[8][132];
    __shared__ __align__(16) float Bs[8][132];
    const int t  = threadIdx.x;
    const int m0 = blockIdx.y * 128;
    const int n0 = blockIdx.x * 128;
    const int tx = t & 15, ty = t >> 4;
    const int lr = t >> 1;
    const int lc = (t & 1) * 4;
    const float* arow = wa + (size_t)(m0 + lr) * Ee;
    const float* brow = w + (size_t)(n0 + lr) * Ee;
    float acc[8][8];
#pragma unroll
    for (int i = 0; i < 8; i++)
#pragma unroll
        for (int j = 0; j < 8; j++) acc[i][j] = 0.f;

    for (int k0 = 0; k0 < Ee; k0 += 8) {
        float4 a4 = *(const float4*)(arow + k0 + lc);
        float4 b4 = *(const float4*)(brow + k0 + lc);
        __syncthreads();
        As[lc+0][lr] = a4.x; As[lc+1][lr] = a4.y; As[lc+2][lr] = a4.z; As[lc+3][lr] = a4.w;
        Bs[lc+0][lr] = b4.x; Bs[lc+1][lr] = b4.y; Bs[lc+2][lr] = b4.z; Bs[lc+3][lr] = b4.w;
        __syncthreads();
#pragma unroll
        for (int kk = 0; kk < 8; kk++) {
            float a[8], bv[8];
            *(float4*)&a[0]  = *(const float4*)&As[kk][ty*8];
            *(float4*)&a[4]  = *(const float4*)&As[kk][ty*8+4];
            *(float4*)&bv[0] = *(const float4*)&Bs[kk][tx*8];
            *(float4*)&bv[4] = *(const float4*)&Bs[kk][tx*8+4];
#pragma unroll
            for (int i = 0; i < 8; i++)
#pragma unroll
                for (int j = 0; j < 8; j++) acc[i][j] += a[i] * bv[j];
        }
    }
    const int n_base = n0 + tx*8;
    float bz[8];
#pragma unroll
    for (int j = 0; j < 8; j++) bz[j] = bias[n_base + j];
#pragma unroll
    for (int i = 0; i < 8; i++) {
        int m  = m0 + ty*8 + i;
        int b2 = m >> 11, s2 = m & 2047;
        float* drow = outp + (size_t)(s2*Bb + b2)*Ee + n_base;
        float4 o1 = {acc[i][0]+bz[0], acc[i][1]+bz[1], acc[i][2]+bz[2], acc[i][3]+bz[3]};
        float4 o2 = {acc[i][4]+bz[4], acc[i][5]+bz[5], acc[i][6]+bz[6], acc[i][7]+bz[7]};
        *(float4*)(drow)     = o1;
        *(float4*)(drow + 4) = o2;
    }
}

extern "C" void kernel_launch(void* const* d_in, const int* in_sizes, int n_in,
                              void* d_out, int out_size, void* d_ws, size_t ws_size,
                              hipStream_t stream) {
    const float*         x         = (const float*)d_in[0];
    const float*         attn_mask = (const float*)d_in[1];
    const unsigned char* kpm       = (const unsigned char*)d_in[2];
    const float*         qkv_w     = (const float*)d_in[3];
    const float*         qkv_b     = (const float*)d_in[4];
    const float*         out_w     = (const float*)d_in[5];
    const float*         out_b     = (const float*)d_in[6];

    float* outp      = (float*)d_out;
    float* attn_mean = outp + 4194304;          // S*B*E

    __hip_bfloat16* Qp = (__hip_bfloat16*)d_ws;          // 8 MB
    __hip_bfloat16* Kp = Qp + 4194304;                   // 8 MB
    __hip_bfloat16* Vt = Kp + 4194304;                   // 8 MB (transposed [B,H,D,S])
    float* wa    = (float*)(Vt + 4194304);               // 16 MB
    float* rlbuf = wa + 4194304;                         // 256 KB

    qkv_gemm<<<dim3(24, 32), 256, 0, stream>>>(x, qkv_w, qkv_b, Qp, Kp, Vt);
    attn_mfma<<<dim3(1024), 256, 0, stream>>>(Qp, Kp, Vt, attn_mask, kpm, wa, rlbuf);
    attn_mean_k<<<dim3(4, 128, Bb), 256, 0, stream>>>(Qp, Kp, attn_mask, kpm, rlbuf, attn_mean);
    out_gemm<<<dim3(8, 32), 256, 0, stream>>>(wa, out_w, out_b, outp);
}

// Round 3
// 568.304 us; speedup vs baseline: 4.1412x; 1.7829x over previous
//
#include <hip/hip_runtime.h>
#include <hip/hip_bf16.h>

// MHA forward, round 3: bf16 MFMA everywhere + mask fast-path flag.
// S=2048 B=2 E=1024 H=16 D=64. scale = 1/8.
// ws (48.3 MB): xb bf16[4096][1024] | qwb bf16[3072][1024] | owb bf16[1024][1024]
//   | Qp bf16[B,H,S,64] | Kp bf16[B,H,S,64] | Vt bf16[B,H,64,S]
//   | wa bf16[B*S][E] | rl fp32[B,H,S] | flag u32
// d_out: out[S,B,E] fp32 (4194304) then attn_mean[B,S,S] fp32 (8388608).

#define Sq 2048
#define Bb 2
#define Ee 1024
#define Hh 16
#define Dd 64

typedef __attribute__((ext_vector_type(8))) short bhalf8;   // 8 bf16 (4 VGPRs)
typedef __attribute__((ext_vector_type(4))) float f32x4;

__device__ __forceinline__ void gld16(const __hip_bfloat16* g, __hip_bfloat16* l) {
    __builtin_amdgcn_global_load_lds(
        (const __attribute__((address_space(1))) unsigned int*)g,
        (__attribute__((address_space(3))) unsigned int*)l, 16, 0, 0);
}

// ---------------- prep: fp32 -> bf16 conversions ----------------
__global__ __launch_bounds__(256) void convx_k(const float* __restrict__ x,
                                               __hip_bfloat16* __restrict__ xb) {
    const int m = blockIdx.x;                 // m = b*2048 + s
    const int e = threadIdx.x * 4;
    const int b = m >> 11, s = m & 2047;
    float4 v = *(const float4*)(x + ((size_t)s*Bb + b)*Ee + e);
    alignas(8) __hip_bfloat16 o[4] = {__float2bfloat16(v.x), __float2bfloat16(v.y),
                                      __float2bfloat16(v.z), __float2bfloat16(v.w)};
    *(uint2*)(xb + (size_t)m*Ee + e) = *(const uint2*)o;
}

__global__ __launch_bounds__(256) void convw_k(const float* __restrict__ src,
                                               __hip_bfloat16* __restrict__ dst, int n4) {
    int i = blockIdx.x*256 + threadIdx.x;
    if (i < n4) {
        float4 v = ((const float4*)src)[i];
        alignas(8) __hip_bfloat16 o[4] = {__float2bfloat16(v.x), __float2bfloat16(v.y),
                                          __float2bfloat16(v.z), __float2bfloat16(v.w)};
        ((uint2*)dst)[i] = *(const uint2*)o;
    }
}

// ---------------- prep: detect nonzero masks ----------------
__global__ __launch_bounds__(256) void maskflag_k(const float* __restrict__ am,
                                                  const unsigned int* __restrict__ kpm32,
                                                  unsigned int* __restrict__ flag) {
    const int g = blockIdx.x*256 + threadIdx.x;    // 4096 blocks -> g < 1048576
    float4 v = ((const float4*)am)[g];
    bool nz = (v.x != 0.f) | (v.y != 0.f) | (v.z != 0.f) | (v.w != 0.f);
    if (g < (Bb*Sq)/4) nz |= (kpm32[g] != 0u);
    if (__ballot(nz)) { if ((threadIdx.x & 63) == 0) atomicOr(flag, 1u); }
}

// ---------------- GEMM 1: QKV projection, bf16 MFMA, scatter epilogue ----------------
// C[4096][3072] = xb @ qwb^T + bias; Q,K -> [B,H,S,64], V -> transposed [B,H,64,S].
__global__ __launch_bounds__(256) void gemm_qkv(
    const __hip_bfloat16* __restrict__ A, const __hip_bfloat16* __restrict__ Bw,
    const float* __restrict__ bias,
    __hip_bfloat16* __restrict__ Qp, __hip_bfloat16* __restrict__ Kp,
    __hip_bfloat16* __restrict__ Vt)
{
    __shared__ __align__(16) __hip_bfloat16 As[128*32];
    __shared__ __align__(16) __hip_bfloat16 Bs[128*32];
    const int t = threadIdx.x;
    const int l = t & 63, lm = l & 15, quad = l >> 4;
    const int w = t >> 6;
    const int mw = (w & 1)*64, nw = (w >> 1)*64;
    const int m0 = blockIdx.y*128, n0 = blockIdx.x*128;

    const int srow = t >> 2;              // 0..63
    const int scol = (t & 3)*8;
    const __hip_bfloat16* ag = A  + (size_t)(m0 + srow)*1024 + scol;
    const __hip_bfloat16* bg = Bw + (size_t)(n0 + srow)*1024 + scol;
    __hip_bfloat16* al = As + t*8;
    __hip_bfloat16* bl = Bs + t*8;

    f32x4 acc[4][4] = {};
    for (int k0 = 0; k0 < 1024; k0 += 32) {
        __syncthreads();
        gld16(ag + k0, al);
        gld16(ag + (size_t)64*1024 + k0, al + 2048);
        gld16(bg + k0, bl);
        gld16(bg + (size_t)64*1024 + k0, bl + 2048);
        __syncthreads();
        bhalf8 af[4], bf[4];
#pragma unroll
        for (int i = 0; i < 4; i++) {
            af[i] = *(const bhalf8*)&As[(mw + i*16 + lm)*32 + quad*8];
            bf[i] = *(const bhalf8*)&Bs[(nw + i*16 + lm)*32 + quad*8];
        }
#pragma unroll
        for (int mf = 0; mf < 4; mf++)
#pragma unroll
            for (int nf = 0; nf < 4; nf++)
                acc[mf][nf] = __builtin_amdgcn_mfma_f32_16x16x32_bf16(af[mf], bf[nf], acc[mf][nf], 0,0,0);
    }
#pragma unroll
    for (int nf = 0; nf < 4; nf++) {
        const int n = n0 + nw + nf*16 + lm;
        const float bz = bias[n];
        const int which = n >> 10, hh = (n >> 6) & 15, dd = n & 63;
#pragma unroll
        for (int mf = 0; mf < 4; mf++)
#pragma unroll
            for (int r = 0; r < 4; r++) {
                const int m = m0 + mw + mf*16 + quad*4 + r;
                const int b2 = m >> 11, s2 = m & 2047;
                const __hip_bfloat16 v = __float2bfloat16(acc[mf][nf][r] + bz);
                if (which == 0)      Qp[((size_t)(b2*Hh + hh)*Sq + s2)*Dd + dd] = v;
                else if (which == 1) Kp[((size_t)(b2*Hh + hh)*Sq + s2)*Dd + dd] = v;
                else                 Vt[((size_t)(b2*Hh + hh)*Dd + dd)*Sq + s2] = v;
            }
    }
}

// ---------------- Attention core: block=(b,h,64q), 4 waves, K prefetch ----------------
__global__ __launch_bounds__(256) void attn_mfma(
    const __hip_bfloat16* __restrict__ Qp, const __hip_bfloat16* __restrict__ Kp,
    const __hip_bfloat16* __restrict__ Vt,
    const float* __restrict__ am, const unsigned char* __restrict__ kpm,
    const unsigned int* __restrict__ flag,
    __hip_bfloat16* __restrict__ wa, float* __restrict__ rlbuf)
{
    __shared__ __align__(16) __hip_bfloat16 P_lds[4][16][72];
    const int t = threadIdx.x;
    const int w = t >> 6, l = t & 63, lm = l & 15, quad = l >> 4;
    const int blk = blockIdx.x, bh = blk >> 5, b = bh >> 4, h = bh & 15;
    const int q0 = (blk & 31)*64 + w*16;
    const int qrow = q0 + quad*4;
    const bool masked = (flag[0] != 0u);

    const __hip_bfloat16* qbase = Qp + ((size_t)bh*Sq + q0)*Dd;
    const __hip_bfloat16* kbase = Kp + (size_t)bh*Sq*Dd;
    const __hip_bfloat16* vbase = Vt + (size_t)bh*Dd*Sq;

    bhalf8 aq[2];
    aq[0] = *(const bhalf8*)(qbase + lm*Dd + quad*8);
    aq[1] = *(const bhalf8*)(qbase + lm*Dd + quad*8 + 32);

    f32x4 o[4] = {};
    float lsum[4] = {0.f, 0.f, 0.f, 0.f};

    bhalf8 bk[8];
#pragma unroll
    for (int f = 0; f < 2; f++)
#pragma unroll
        for (int j = 0; j < 4; j++)
            bk[f*4+j] = *(const bhalf8*)(kbase + (size_t)(j*16 + lm)*Dd + quad*8 + f*32);

    for (int kt = 0; kt < 32; kt++) {
        const int k0 = kt*64;
        // V loads for current tile (consumed at bottom: full-iteration latency cover)
        bhalf8 bv[8];
#pragma unroll
        for (int ks = 0; ks < 2; ks++)
#pragma unroll
            for (int nd = 0; nd < 4; nd++)
                bv[ks*4+nd] = *(const bhalf8*)(vbase + (size_t)(nd*16+lm)*Sq + k0 + ks*32 + quad*8);
        // K prefetch for next tile (clamped redundant load on last iter)
        const int k1 = (kt < 31) ? k0 + 64 : k0;
        bhalf8 nk[8];
#pragma unroll
        for (int f = 0; f < 2; f++)
#pragma unroll
            for (int j = 0; j < 4; j++)
                nk[f*4+j] = *(const bhalf8*)(kbase + (size_t)(k1 + j*16 + lm)*Dd + quad*8 + f*32);

        f32x4 s[4] = {};
#pragma unroll
        for (int f = 0; f < 2; f++)
#pragma unroll
            for (int j = 0; j < 4; j++)
                s[j] = __builtin_amdgcn_mfma_f32_16x16x32_bf16(aq[f], bk[f*4+j], s[j], 0,0,0);

#pragma unroll
        for (int j = 0; j < 4; j++) {
            const int key = k0 + j*16 + lm;
            float kmv = 0.f;
            if (masked) kmv = kpm[b*Sq + key] ? -1e30f : 0.0f;
#pragma unroll
            for (int r = 0; r < 4; r++) {
                float sv = s[j][r]*0.125f;
                if (masked) sv += am[(size_t)(qrow + r)*Sq + key] + kmv;
                float p = __expf(sv);
                lsum[r] += p;
                P_lds[w][quad*4 + r][j*16 + lm] = __float2bfloat16(p);
            }
        }
#pragma unroll
        for (int ks = 0; ks < 2; ks++) {
            bhalf8 ap = *(const bhalf8*)&P_lds[w][lm][ks*32 + quad*8];
#pragma unroll
            for (int nd = 0; nd < 4; nd++)
                o[nd] = __builtin_amdgcn_mfma_f32_16x16x32_bf16(ap, bv[ks*4+nd], o[nd], 0,0,0);
        }
#pragma unroll
        for (int i = 0; i < 8; i++) bk[i] = nk[i];
    }
    float rl[4];
#pragma unroll
    for (int r = 0; r < 4; r++) {
        float v = lsum[r];
        v += __shfl_xor(v, 1, 64);
        v += __shfl_xor(v, 2, 64);
        v += __shfl_xor(v, 4, 64);
        v += __shfl_xor(v, 8, 64);
        rl[r] = 1.0f / v;
    }
    if (lm == 0) {
#pragma unroll
        for (int r = 0; r < 4; r++) rlbuf[(size_t)bh*Sq + qrow + r] = rl[r];
    }
#pragma unroll
    for (int nd = 0; nd < 4; nd++)
#pragma unroll
        for (int r = 0; r < 4; r++)
            wa[((size_t)b*Sq + qrow + r)*Ee + h*Dd + nd*16 + lm] =
                __float2bfloat16(o[nd][r] * rl[r]);
}

// ---------------- attn_mean by recomputation ----------------
__global__ __launch_bounds__(256) void attn_mean_k(
    const __hip_bfloat16* __restrict__ Qp, const __hip_bfloat16* __restrict__ Kp,
    const float* __restrict__ am, const unsigned char* __restrict__ kpm,
    const unsigned int* __restrict__ flag,
    const float* __restrict__ rlbuf, float* __restrict__ attn_mean)
{
    const int t = threadIdx.x;
    const int w = t >> 6, l = t & 63, lm = l & 15, quad = l >> 4;
    const int b = blockIdx.z;
    const int q0 = blockIdx.y * 16;
    const int kc = blockIdx.x * 512 + w * 128;
    const int qrow = q0 + quad * 4;
    const bool masked = (flag[0] != 0u);

    float mval[2][4][4];
    if (masked) {
#pragma unroll
        for (int kt = 0; kt < 2; kt++)
#pragma unroll
            for (int j = 0; j < 4; j++) {
                const int key = kc + kt*64 + j*16 + lm;
                const float km = kpm[b*Sq + key] ? -1e30f : 0.0f;
#pragma unroll
                for (int r = 0; r < 4; r++)
                    mval[kt][j][r] = am[(size_t)(qrow + r)*Sq + key] + km;
            }
    } else {
#pragma unroll
        for (int kt = 0; kt < 2; kt++)
#pragma unroll
            for (int j = 0; j < 4; j++)
#pragma unroll
                for (int r = 0; r < 4; r++) mval[kt][j][r] = 0.f;
    }

    float macc[2][4][4];
#pragma unroll
    for (int kt = 0; kt < 2; kt++)
#pragma unroll
        for (int j = 0; j < 4; j++)
#pragma unroll
            for (int r = 0; r < 4; r++) macc[kt][j][r] = 0.f;

#pragma unroll 2
    for (int h = 0; h < Hh; h++) {
        const int bh = b*Hh + h;
        const __hip_bfloat16* qbase = Qp + ((size_t)bh*Sq + q0)*Dd;
        const __hip_bfloat16* kbase = Kp + (size_t)bh*Sq*Dd;
        bhalf8 aq0 = *(const bhalf8*)(qbase + lm*Dd + quad*8);
        bhalf8 aq1 = *(const bhalf8*)(qbase + lm*Dd + quad*8 + 32);
        float rl4[4];
#pragma unroll
        for (int r = 0; r < 4; r++)
            rl4[r] = rlbuf[(size_t)bh*Sq + qrow + r] * 0.0625f;   // /H
#pragma unroll
        for (int kt = 0; kt < 2; kt++) {
            const int k0 = kc + kt*64;
            f32x4 s[4] = {};
#pragma unroll
            for (int j = 0; j < 4; j++) {
                bhalf8 bk0 = *(const bhalf8*)(kbase + (size_t)(k0 + j*16 + lm)*Dd + quad*8);
                s[j] = __builtin_amdgcn_mfma_f32_16x16x32_bf16(aq0, bk0, s[j], 0, 0, 0);
                bhalf8 bk1 = *(const bhalf8*)(kbase + (size_t)(k0 + j*16 + lm)*Dd + quad*8 + 32);
                s[j] = __builtin_amdgcn_mfma_f32_16x16x32_bf16(aq1, bk1, s[j], 0, 0, 0);
            }
#pragma unroll
            for (int j = 0; j < 4; j++)
#pragma unroll
                for (int r = 0; r < 4; r++)
                    macc[kt][j][r] += __expf(s[j][r]*0.125f + mval[kt][j][r]) * rl4[r];
        }
    }
#pragma unroll
    for (int kt = 0; kt < 2; kt++)
#pragma unroll
        for (int j = 0; j < 4; j++)
#pragma unroll
            for (int r = 0; r < 4; r++)
                attn_mean[((size_t)b*Sq + qrow + r)*Sq + kc + kt*64 + j*16 + lm] =
                    macc[kt][j][r];
}

// ---------------- GEMM 2: output projection, bf16 MFMA ----------------
__global__ __launch_bounds__(256) void gemm_out(
    const __hip_bfloat16* __restrict__ A, const __hip_bfloat16* __restrict__ Bw,
    const float* __restrict__ bias, float* __restrict__ outp)
{
    __shared__ __align__(16) __hip_bfloat16 As[128*32];
    __shared__ __align__(16) __hip_bfloat16 Bs[128*32];
    const int t = threadIdx.x;
    const int l = t & 63, lm = l & 15, quad = l >> 4;
    const int w = t >> 6;
    const int mw = (w & 1)*64, nw = (w >> 1)*64;
    const int m0 = blockIdx.y*128, n0 = blockIdx.x*128;

    const int srow = t >> 2;
    const int scol = (t & 3)*8;
    const __hip_bfloat16* ag = A  + (size_t)(m0 + srow)*1024 + scol;
    const __hip_bfloat16* bg = Bw + (size_t)(n0 + srow)*1024 + scol;
    __hip_bfloat16* al = As + t*8;
    __hip_bfloat16* bl = Bs + t*8;

    f32x4 acc[4][4] = {};
    for (int k0 = 0; k0 < 1024; k0 += 32) {
        __syncthreads();
        gld16(ag + k0, al);
        gld16(ag + (size_t)64*1024 + k0, al + 2048);
        gld16(bg + k0, bl);
        gld16(bg + (size_t)64*1024 + k0, bl + 2048);
        __syncthreads();
        bhalf8 af[4], bf[4];
#pragma unroll
        for (int i = 0; i < 4; i++) {
            af[i] = *(const bhalf8*)&As[(mw + i*16 + lm)*32 + quad*8];
            bf[i] = *(const bhalf8*)&Bs[(nw + i*16 + lm)*32 + quad*8];
        }
#pragma unroll
        for (int mf = 0; mf < 4; mf++)
#pragma unroll
            for (int nf = 0; nf < 4; nf++)
                acc[mf][nf] = __builtin_amdgcn_mfma_f32_16x16x32_bf16(af[mf], bf[nf], acc[mf][nf], 0,0,0);
    }
#pragma unroll
    for (int nf = 0; nf < 4; nf++) {
        const int n = n0 + nw + nf*16 + lm;
        const float bz = bias[n];
#pragma unroll
        for (int mf = 0; mf < 4; mf++)
#pragma unroll
            for (int r = 0; r < 4; r++) {
                const int m = m0 + mw + mf*16 + quad*4 + r;
                const int b2 = m >> 11, s2 = m & 2047;
                outp[((size_t)s2*Bb + b2)*Ee + n] = acc[mf][nf][r] + bz;
            }
    }
}

extern "C" void kernel_launch(void* const* d_in, const int* in_sizes, int n_in,
                              void* d_out, int out_size, void* d_ws, size_t ws_size,
                              hipStream_t stream) {
    const float*         x         = (const float*)d_in[0];
    const float*         attn_mask = (const float*)d_in[1];
    const unsigned char* kpm       = (const unsigned char*)d_in[2];
    const float*         qkv_w     = (const float*)d_in[3];
    const float*         qkv_b     = (const float*)d_in[4];
    const float*         out_w     = (const float*)d_in[5];
    const float*         out_b     = (const float*)d_in[6];

    float* outp      = (float*)d_out;
    float* attn_mean = outp + 4194304;          // S*B*E

    __hip_bfloat16* xb  = (__hip_bfloat16*)d_ws;     // 8 MB
    __hip_bfloat16* qwb = xb  + 4194304;             // 6 MB
    __hip_bfloat16* owb = qwb + 3145728;             // 2 MB
    __hip_bfloat16* Qp  = owb + 1048576;             // 8 MB
    __hip_bfloat16* Kp  = Qp  + 4194304;             // 8 MB
    __hip_bfloat16* Vt  = Kp  + 4194304;             // 8 MB (transposed [B,H,D,S])
    __hip_bfloat16* wab = Vt  + 4194304;             // 8 MB
    float* rlbuf        = (float*)(wab + 4194304);   // 256 KB
    unsigned int* flag  = (unsigned int*)(rlbuf + 65536);

    hipMemsetAsync(flag, 0, sizeof(unsigned int), stream);
    maskflag_k<<<4096, 256, 0, stream>>>(attn_mask, (const unsigned int*)kpm, flag);
    convx_k<<<4096, 256, 0, stream>>>(x, xb);
    convw_k<<<3072, 256, 0, stream>>>(qkv_w, qwb, 786432);
    convw_k<<<1024, 256, 0, stream>>>(out_w, owb, 262144);
    gemm_qkv<<<dim3(24, 32), 256, 0, stream>>>(xb, qwb, qkv_b, Qp, Kp, Vt);
    attn_mfma<<<dim3(1024), 256, 0, stream>>>(Qp, Kp, Vt, attn_mask, kpm, flag, wab, rlbuf);
    attn_mean_k<<<dim3(4, 128, Bb), 256, 0, stream>>>(Qp, Kp, attn_mask, kpm, flag, rlbuf, attn_mean);
    gemm_out<<<dim3(8, 32), 256, 0, stream>>>(wab, owb, out_b, outp);
}

// Round 4
// 539.804 us; speedup vs baseline: 4.3599x; 1.0528x over previous
//
#include <hip/hip_runtime.h>
#include <hip/hip_bf16.h>

// MHA forward, round 4: shfl-transposed flash attention (no LDS, no barriers),
// leaner recompute attn_mean, fused prep.
// S=2048 B=2 E=1024 H=16 D=64. scale = 1/8.
// ws (48.3 MB): xb bf16[4096][1024] | qwb bf16[3072][1024] | owb bf16[1024][1024]
//   | Qp bf16[B,H,S,64] | Kp bf16[B,H,S,64] | Vt bf16[B,H,64,S]
//   | wa bf16[B*S][E] | rl fp32[B,H,S] | flag u32
// d_out: out[S,B,E] fp32 (4194304) then attn_mean[B,S,S] fp32 (8388608).

#define Sq 2048
#define Bb 2
#define Ee 1024
#define Hh 16
#define Dd 64

typedef __attribute__((ext_vector_type(8))) short bhalf8;   // 8 bf16 (4 VGPRs)
typedef __attribute__((ext_vector_type(4))) float f32x4;

__device__ __forceinline__ void gld16(const __hip_bfloat16* g, __hip_bfloat16* l) {
    __builtin_amdgcn_global_load_lds(
        (const __attribute__((address_space(1))) unsigned int*)g,
        (__attribute__((address_space(3))) unsigned int*)l, 16, 0, 0);
}

__device__ __forceinline__ int pkbf(float a, float b) {
    union { __hip_bfloat16 h[2]; int i; } u;
    u.h[0] = __float2bfloat16(a);
    u.h[1] = __float2bfloat16(b);
    return u.i;
}

// ---------------- fused prep: mask scan + fp32->bf16 conversions ----------------
__global__ __launch_bounds__(256) void prep_k(
    const float* __restrict__ x, const float* __restrict__ am,
    const unsigned int* __restrict__ kpm32,
    const float* __restrict__ qkv_w, const float* __restrict__ out_w,
    __hip_bfloat16* __restrict__ xb, __hip_bfloat16* __restrict__ qwb,
    __hip_bfloat16* __restrict__ owb, unsigned int* __restrict__ flag)
{
    const long i = (long)blockIdx.x*256 + threadIdx.x;
    if (i < 1048576) {                       // mask scan (am 1M float4, kpm 1024 u32)
        float4 v = ((const float4*)am)[i];
        bool nz = (v.x != 0.f) | (v.y != 0.f) | (v.z != 0.f) | (v.w != 0.f);
        if (i < 1024) nz |= (kpm32[i] != 0u);
        if (__ballot(nz)) { if ((threadIdx.x & 63) == 0) atomicOr(flag, 1u); }
    } else if (i < 2097152) {                // x conv with [S,B,E]->[B*S][E]
        const long j = i - 1048576;
        const int m = (int)(j >> 8), e4 = (int)(j & 255);
        const int b = m >> 11, s = m & 2047;
        float4 v = ((const float4*)x)[(size_t)(s*Bb + b)*256 + e4];
        union { __hip_bfloat16 h[4]; uint2 u; } o;
        o.h[0]=__float2bfloat16(v.x); o.h[1]=__float2bfloat16(v.y);
        o.h[2]=__float2bfloat16(v.z); o.h[3]=__float2bfloat16(v.w);
        ((uint2*)xb)[(size_t)m*256 + e4] = o.u;
    } else if (i < 2883584) {                // qkv_w conv (786432 float4)
        const long j = i - 2097152;
        float4 v = ((const float4*)qkv_w)[j];
        union { __hip_bfloat16 h[4]; uint2 u; } o;
        o.h[0]=__float2bfloat16(v.x); o.h[1]=__float2bfloat16(v.y);
        o.h[2]=__float2bfloat16(v.z); o.h[3]=__float2bfloat16(v.w);
        ((uint2*)qwb)[j] = o.u;
    } else if (i < 3145728) {                // out_w conv (262144 float4)
        const long j = i - 2883584;
        float4 v = ((const float4*)out_w)[j];
        union { __hip_bfloat16 h[4]; uint2 u; } o;
        o.h[0]=__float2bfloat16(v.x); o.h[1]=__float2bfloat16(v.y);
        o.h[2]=__float2bfloat16(v.z); o.h[3]=__float2bfloat16(v.w);
        ((uint2*)owb)[j] = o.u;
    }
}

// ---------------- GEMM 1: QKV projection, bf16 MFMA, scatter epilogue ----------------
__global__ __launch_bounds__(256) void gemm_qkv(
    const __hip_bfloat16* __restrict__ A, const __hip_bfloat16* __restrict__ Bw,
    const float* __restrict__ bias,
    __hip_bfloat16* __restrict__ Qp, __hip_bfloat16* __restrict__ Kp,
    __hip_bfloat16* __restrict__ Vt)
{
    __shared__ __align__(16) __hip_bfloat16 As[128*32];
    __shared__ __align__(16) __hip_bfloat16 Bs[128*32];
    const int t = threadIdx.x;
    const int l = t & 63, lm = l & 15, quad = l >> 4;
    const int w = t >> 6;
    const int mw = (w & 1)*64, nw = (w >> 1)*64;
    const int m0 = blockIdx.y*128, n0 = blockIdx.x*128;

    const int srow = t >> 2;              // 0..63
    const int scol = (t & 3)*8;
    const __hip_bfloat16* ag = A  + (size_t)(m0 + srow)*1024 + scol;
    const __hip_bfloat16* bg = Bw + (size_t)(n0 + srow)*1024 + scol;
    __hip_bfloat16* al = As + t*8;
    __hip_bfloat16* bl = Bs + t*8;

    f32x4 acc[4][4] = {};
    for (int k0 = 0; k0 < 1024; k0 += 32) {
        __syncthreads();
        gld16(ag + k0, al);
        gld16(ag + (size_t)64*1024 + k0, al + 2048);
        gld16(bg + k0, bl);
        gld16(bg + (size_t)64*1024 + k0, bl + 2048);
        __syncthreads();
        bhalf8 af[4], bf[4];
#pragma unroll
        for (int i = 0; i < 4; i++) {
            af[i] = *(const bhalf8*)&As[(mw + i*16 + lm)*32 + quad*8];
            bf[i] = *(const bhalf8*)&Bs[(nw + i*16 + lm)*32 + quad*8];
        }
#pragma unroll
        for (int mf = 0; mf < 4; mf++)
#pragma unroll
            for (int nf = 0; nf < 4; nf++)
                acc[mf][nf] = __builtin_amdgcn_mfma_f32_16x16x32_bf16(af[mf], bf[nf], acc[mf][nf], 0,0,0);
    }
#pragma unroll
    for (int nf = 0; nf < 4; nf++) {
        const int n = n0 + nw + nf*16 + lm;
        const float bz = bias[n];
        const int which = n >> 10, hh = (n >> 6) & 15, dd = n & 63;
#pragma unroll
        for (int mf = 0; mf < 4; mf++)
#pragma unroll
            for (int r = 0; r < 4; r++) {
                const int m = m0 + mw + mf*16 + quad*4 + r;
                const int b2 = m >> 11, s2 = m & 2047;
                const __hip_bfloat16 v = __float2bfloat16(acc[mf][nf][r] + bz);
                if (which == 0)      Qp[((size_t)(b2*Hh + hh)*Sq + s2)*Dd + dd] = v;
                else if (which == 1) Kp[((size_t)(b2*Hh + hh)*Sq + s2)*Dd + dd] = v;
                else                 Vt[((size_t)(b2*Hh + hh)*Dd + dd)*Sq + s2] = v;
            }
    }
}

// ---------------- Attention core: S^T orientation, shfl transpose, no LDS ----------------
// Block = (bh, 64 q rows); wave w owns q rows [qt*64 + w*16, +16); lane's q = q0w + lm.
__global__ __launch_bounds__(256, 4) void attn_mfma(
    const __hip_bfloat16* __restrict__ Qp, const __hip_bfloat16* __restrict__ Kp,
    const __hip_bfloat16* __restrict__ Vt,
    const float* __restrict__ am, const unsigned char* __restrict__ kpm,
    const unsigned int* __restrict__ flag,
    __hip_bfloat16* __restrict__ wa, float* __restrict__ rlbuf)
{
    const int t = threadIdx.x;
    const int w = t >> 6, l = t & 63, lm = l & 15, quad = l >> 4;
    const int blk = blockIdx.x, bh = blk >> 5, b = bh >> 4, h = bh & 15;
    const int q = (blk & 31)*64 + w*16 + lm;       // this lane's q row
    const bool masked = (flag[0] != 0u);

    const __hip_bfloat16* qbase = Qp + (size_t)bh*Sq*Dd;
    const __hip_bfloat16* kbase = Kp + (size_t)bh*Sq*Dd;
    const __hip_bfloat16* vbase = Vt + (size_t)bh*Dd*Sq;

    // Q as B-operand: B[k=d][n=q], lane n=lm -> q, k=quad*8+jj (+f*32)
    bhalf8 bq[2];
    bq[0] = *(const bhalf8*)(qbase + (size_t)q*Dd + quad*8);
    bq[1] = *(const bhalf8*)(qbase + (size_t)q*Dd + quad*8 + 32);

    f32x4 o[4] = {};            // O^T: tile nd -> rows d = nd*16+quad*4+r, col q=lm
    float lsum = 0.f;

    // K as A-operand: A[m=key][k=d]; preload kt=0
    bhalf8 ak[8];
#pragma unroll
    for (int f = 0; f < 2; f++)
#pragma unroll
        for (int j = 0; j < 4; j++)
            ak[f*4+j] = *(const bhalf8*)(kbase + (size_t)(j*16 + lm)*Dd + quad*8 + f*32);

    for (int kt = 0; kt < 32; kt++) {
        const int k0 = kt*64;
        // V^T A-frags for this tile (consumed at bottom)
        bhalf8 av[8];
#pragma unroll
        for (int ks = 0; ks < 2; ks++)
#pragma unroll
            for (int nd = 0; nd < 4; nd++)
                av[ks*4+nd] = *(const bhalf8*)(vbase + (size_t)(nd*16+lm)*Sq + k0 + ks*32 + quad*8);

        // S^T = K · Q^T : tile j covers keys [k0+j*16, +16)
        f32x4 s[4] = {};
#pragma unroll
        for (int f = 0; f < 2; f++)
#pragma unroll
            for (int j = 0; j < 4; j++)
                s[j] = __builtin_amdgcn_mfma_f32_16x16x32_bf16(ak[f*4+j], bq[f], s[j], 0,0,0);

        // K prefetch for next tile, in place (ak consumed above)
        const int k1 = (kt < 31) ? k0 + 64 : k0;
#pragma unroll
        for (int f = 0; f < 2; f++)
#pragma unroll
            for (int j = 0; j < 4; j++)
                ak[f*4+j] = *(const bhalf8*)(kbase + (size_t)(k1 + j*16 + lm)*Dd + quad*8 + f*32);

        // exp + pack to bf16 pairs. Lane holds keys k0 + j*16 + quad*4 + r, all for q.
        int pk[4][2];
#pragma unroll
        for (int j = 0; j < 4; j++) {
            float p[4];
#pragma unroll
            for (int r = 0; r < 4; r++) {
                float sv = s[j][r]*0.125f;
                if (masked) {
                    const int key = k0 + j*16 + quad*4 + r;
                    const float km = kpm[b*Sq + key] ? -1e30f : 0.0f;
                    sv += am[(size_t)q*Sq + key] + km;
                }
                p[r] = __expf(sv);
            }
            lsum += (p[0]+p[1]) + (p[2]+p[3]);
            pk[j][0] = pkbf(p[0], p[1]);
            pk[j][1] = pkbf(p[2], p[3]);
        }

        // PV: O^T += V^T · P^T. Build P^T B-frags by cross-lane pull.
#pragma unroll
        for (int ks = 0; ks < 2; ks++) {
            union { int i[4]; bhalf8 v; } bp;
#pragma unroll
            for (int g = 0; g < 4; g++) {
                const int src = (2*(quad & 1) + (g >> 1))*16 + lm;
                const int t0 = __shfl(pk[2*ks    ][g & 1], src, 64);
                const int t1 = __shfl(pk[2*ks + 1][g & 1], src, 64);
                bp.i[g] = (quad >= 2) ? t1 : t0;
            }
#pragma unroll
            for (int nd = 0; nd < 4; nd++)
                o[nd] = __builtin_amdgcn_mfma_f32_16x16x32_bf16(av[ks*4+nd], bp.v, o[nd], 0,0,0);
        }
    }

    // row sum: lane's lsum covers its quad's key subset; reduce across quads (same lm=q)
    lsum += __shfl_xor(lsum, 16, 64);
    lsum += __shfl_xor(lsum, 32, 64);
    const float rl = 1.0f / lsum;
    if (quad == 0) rlbuf[(size_t)bh*Sq + q] = rl;

    // write wa[b][q][h*64 + d], d = nd*16 + quad*4 + r  (packed 4 bf16 = 8 B)
#pragma unroll
    for (int nd = 0; nd < 4; nd++) {
        union { __hip_bfloat16 hx[4]; uint2 u; } ou;
#pragma unroll
        for (int r = 0; r < 4; r++) ou.hx[r] = __float2bfloat16(o[nd][r] * rl);
        *(uint2*)(wa + ((size_t)b*Sq + q)*Ee + h*Dd + nd*16 + quad*4) = ou.u;
    }
}

// ---------------- attn_mean by recomputation: block=(b, 16q, 256 keys), wave=64 keys ----------------
__global__ __launch_bounds__(256) void attn_mean_k(
    const __hip_bfloat16* __restrict__ Qp, const __hip_bfloat16* __restrict__ Kp,
    const float* __restrict__ am, const unsigned char* __restrict__ kpm,
    const unsigned int* __restrict__ flag,
    const float* __restrict__ rlbuf, float* __restrict__ attn_mean)
{
    const int t = threadIdx.x;
    const int w = t >> 6, l = t & 63, lm = l & 15, quad = l >> 4;
    const int b = blockIdx.z;
    const int q0 = blockIdx.y * 16;
    const int kc = blockIdx.x * 256 + w * 64;
    const int qrow = q0 + quad*4;
    const bool masked = (flag[0] != 0u);

    float macc[4][4] = {};

    // preload h=0: Q as A (m=lm -> q0+lm), K as B (n=lm -> key)
    bhalf8 aq[2], bk[8];
    {
        const __hip_bfloat16* qb = Qp + ((size_t)(b*Hh)*Sq + q0)*Dd;
        const __hip_bfloat16* kb = Kp + (size_t)(b*Hh)*Sq*Dd;
        aq[0] = *(const bhalf8*)(qb + (size_t)lm*Dd + quad*8);
        aq[1] = *(const bhalf8*)(qb + (size_t)lm*Dd + quad*8 + 32);
#pragma unroll
        for (int f = 0; f < 2; f++)
#pragma unroll
            for (int j = 0; j < 4; j++)
                bk[f*4+j] = *(const bhalf8*)(kb + (size_t)(kc + j*16 + lm)*Dd + quad*8 + f*32);
    }

    for (int h = 0; h < Hh; h++) {
        const int bh = b*Hh + h;
        float rl4[4];
#pragma unroll
        for (int r = 0; r < 4; r++)
            rl4[r] = rlbuf[(size_t)bh*Sq + qrow + r] * 0.0625f;   // /H

        f32x4 s[4] = {};
#pragma unroll
        for (int f = 0; f < 2; f++)
#pragma unroll
            for (int j = 0; j < 4; j++)
                s[j] = __builtin_amdgcn_mfma_f32_16x16x32_bf16(aq[f], bk[f*4+j], s[j], 0,0,0);

        // prefetch next head's Q/K frags (in place; frags consumed above)
        const int hn = (h < Hh-1) ? h+1 : h;
        {
            const __hip_bfloat16* qb = Qp + ((size_t)(b*Hh + hn)*Sq + q0)*Dd;
            const __hip_bfloat16* kb = Kp + (size_t)(b*Hh + hn)*Sq*Dd;
            aq[0] = *(const bhalf8*)(qb + (size_t)lm*Dd + quad*8);
            aq[1] = *(const bhalf8*)(qb + (size_t)lm*Dd + quad*8 + 32);
#pragma unroll
            for (int f = 0; f < 2; f++)
#pragma unroll
                for (int j = 0; j < 4; j++)
                    bk[f*4+j] = *(const bhalf8*)(kb + (size_t)(kc + j*16 + lm)*Dd + quad*8 + f*32);
        }

#pragma unroll
        for (int j = 0; j < 4; j++)
#pragma unroll
            for (int r = 0; r < 4; r++) {
                float sv = s[j][r]*0.125f;
                if (masked) {
                    const int key = kc + j*16 + lm;
                    const float km = kpm[b*Sq + key] ? -1e30f : 0.0f;
                    sv += am[(size_t)(qrow + r)*Sq + key] + km;
                }
                macc[j][r] += __expf(sv) * rl4[r];
            }
    }
#pragma unroll
    for (int j = 0; j < 4; j++)
#pragma unroll
        for (int r = 0; r < 4; r++)
            attn_mean[((size_t)b*Sq + qrow + r)*Sq + kc + j*16 + lm] = macc[j][r];
}

// ---------------- GEMM 2: output projection, bf16 MFMA ----------------
__global__ __launch_bounds__(256) void gemm_out(
    const __hip_bfloat16* __restrict__ A, const __hip_bfloat16* __restrict__ Bw,
    const float* __restrict__ bias, float* __restrict__ outp)
{
    __shared__ __align__(16) __hip_bfloat16 As[128*32];
    __shared__ __align__(16) __hip_bfloat16 Bs[128*32];
    const int t = threadIdx.x;
    const int l = t & 63, lm = l & 15, quad = l >> 4;
    const int w = t >> 6;
    const int mw = (w & 1)*64, nw = (w >> 1)*64;
    const int m0 = blockIdx.y*128, n0 = blockIdx.x*128;

    const int srow = t >> 2;
    const int scol = (t & 3)*8;
    const __hip_bfloat16* ag = A  + (size_t)(m0 + srow)*1024 + scol;
    const __hip_bfloat16* bg = Bw + (size_t)(n0 + srow)*1024 + scol;
    __hip_bfloat16* al = As + t*8;
    __hip_bfloat16* bl = Bs + t*8;

    f32x4 acc[4][4] = {};
    for (int k0 = 0; k0 < 1024; k0 += 32) {
        __syncthreads();
        gld16(ag + k0, al);
        gld16(ag + (size_t)64*1024 + k0, al + 2048);
        gld16(bg + k0, bl);
        gld16(bg + (size_t)64*1024 + k0, bl + 2048);
        __syncthreads();
        bhalf8 af[4], bf[4];
#pragma unroll
        for (int i = 0; i < 4; i++) {
            af[i] = *(const bhalf8*)&As[(mw + i*16 + lm)*32 + quad*8];
            bf[i] = *(const bhalf8*)&Bs[(nw + i*16 + lm)*32 + quad*8];
        }
#pragma unroll
        for (int mf = 0; mf < 4; mf++)
#pragma unroll
            for (int nf = 0; nf < 4; nf++)
                acc[mf][nf] = __builtin_amdgcn_mfma_f32_16x16x32_bf16(af[mf], bf[nf], acc[mf][nf], 0,0,0);
    }
#pragma unroll
    for (int nf = 0; nf < 4; nf++) {
        const int n = n0 + nw + nf*16 + lm;
        const float bz = bias[n];
#pragma unroll
        for (int mf = 0; mf < 4; mf++)
#pragma unroll
            for (int r = 0; r < 4; r++) {
                const int m = m0 + mw + mf*16 + quad*4 + r;
                const int b2 = m >> 11, s2 = m & 2047;
                outp[((size_t)s2*Bb + b2)*Ee + n] = acc[mf][nf][r] + bz;
            }
    }
}

extern "C" void kernel_launch(void* const* d_in, const int* in_sizes, int n_in,
                              void* d_out, int out_size, void* d_ws, size_t ws_size,
                              hipStream_t stream) {
    const float*         x         = (const float*)d_in[0];
    const float*         attn_mask = (const float*)d_in[1];
    const unsigned char* kpm       = (const unsigned char*)d_in[2];
    const float*         qkv_w     = (const float*)d_in[3];
    const float*         qkv_b     = (const float*)d_in[4];
    const float*         out_w     = (const float*)d_in[5];
    const float*         out_b     = (const float*)d_in[6];

    float* outp      = (float*)d_out;
    float* attn_mean = outp + 4194304;          // S*B*E

    __hip_bfloat16* xb  = (__hip_bfloat16*)d_ws;     // 8 MB
    __hip_bfloat16* qwb = xb  + 4194304;             // 6 MB
    __hip_bfloat16* owb = qwb + 3145728;             // 2 MB
    __hip_bfloat16* Qp  = owb + 1048576;             // 8 MB
    __hip_bfloat16* Kp  = Qp  + 4194304;             // 8 MB
    __hip_bfloat16* Vt  = Kp  + 4194304;             // 8 MB (transposed [B,H,D,S])
    __hip_bfloat16* wab = Vt  + 4194304;             // 8 MB
    float* rlbuf        = (float*)(wab + 4194304);   // 256 KB
    unsigned int* flag  = (unsigned int*)(rlbuf + 65536);

    hipMemsetAsync(flag, 0, sizeof(unsigned int), stream);
    prep_k<<<12288, 256, 0, stream>>>(x, attn_mask, (const unsigned int*)kpm,
                                      qkv_w, out_w, xb, qwb, owb, flag);
    gemm_qkv<<<dim3(24, 32), 256, 0, stream>>>(xb, qwb, qkv_b, Qp, Kp, Vt);
    attn_mfma<<<dim3(1024), 256, 0, stream>>>(Qp, Kp, Vt, attn_mask, kpm, flag, wab, rlbuf);
    attn_mean_k<<<dim3(8, 128, Bb), 256, 0, stream>>>(Qp, Kp, attn_mask, kpm, flag, rlbuf, attn_mean);
    gemm_out<<<dim3(8, 32), 256, 0, stream>>>(wab, owb, out_b, outp);
}